// Round 8
// baseline (300.362 us; speedup 1.0000x reference)
//
#include <hip/hip_runtime.h>

#define N_VEC 131072   // B*H*W
#define DIM   64
#define KCODE 1024
#define HW    4096
#define DHW   262144
#define EPS   0.125f   // near-tie margin (validated r4-r7)
#define WLCAP 32768
#define BLK_ROWS 128   // rows per block; 8 waves, each owns 128 codes
#define PITCH 72       // shorts per LDS row (144 B)
#define CPITCH 65      // floats per rescue-LDS codebook row (odd -> conflict-free)
#define CHUNK_ROWS 256

typedef short short8 __attribute__((ext_vector_type(8)));
typedef float f32x4  __attribute__((ext_vector_type(4)));

// ws layout (bytes):
//   0      : double loss accumulator
//   8      : int flagged counter
//   12     : int done-ticket counter
//   64     : norms f32[1024]
//   8192   : eh  bf16-bits short[65536]
//   139264 : el  bf16-bits short[65536]
//   270336 : worklist int[WLCAP]

__device__ __forceinline__ unsigned short f32_to_bf16_rne(float x) {
    unsigned u = __float_as_uint(x);
    u += 0x7FFFu + ((u >> 16) & 1u);
    return (unsigned short)(u >> 16);
}
__device__ __forceinline__ float bf16_to_f32(unsigned short h) {
    return __uint_as_float((unsigned)h << 16);
}

__global__ __launch_bounds__(256) void vq_prep(
    const float* __restrict__ cb, float* __restrict__ norms,
    short* __restrict__ ehg, short* __restrict__ elg,
    double* __restrict__ loss_acc, int* __restrict__ counter,
    int* __restrict__ done)
{
    const int t = threadIdx.x;
    if (blockIdx.x == 0 && t == 0) { *loss_acc = 0.0; *counter = 0; *done = 0; }

    const int k    = blockIdx.x * 16 + (t >> 4);
    const int part = t & 15;
    const float4 v = *(const float4*)(cb + k * DIM + part * 4);

    float s = 0.f;
    s = fmaf(v.x, v.x, s); s = fmaf(v.y, v.y, s);
    s = fmaf(v.z, v.z, s); s = fmaf(v.w, v.w, s);
    #pragma unroll
    for (int m = 1; m <= 8; m <<= 1) s += __shfl_xor(s, m, 64);
    if (part == 0) norms[k] = s;

    short h[4], l[4];
    const float vv[4] = { v.x, v.y, v.z, v.w };
    #pragma unroll
    for (int j = 0; j < 4; ++j) {
        unsigned short hh = f32_to_bf16_rne(vv[j]);
        unsigned short ll = f32_to_bf16_rne(vv[j] - bf16_to_f32(hh));
        h[j] = (short)hh; l[j] = (short)ll;
    }
    *(short4*)(ehg + k * DIM + part * 4) = make_short4(h[0], h[1], h[2], h[3]);
    *(short4*)(elg + k * DIM + part * 4) = make_short4(l[0], l[1], l[2], l[3]);
}

__global__ __launch_bounds__(512, 2) void vq_main(
    const float* __restrict__ z, const float* __restrict__ cb,
    const float* __restrict__ norms, const short* __restrict__ ehg,
    const short* __restrict__ elg, float* __restrict__ out,
    double* __restrict__ loss_acc, int* __restrict__ counter,
    int* __restrict__ worklist, int cap)
{
    __shared__ short  zh[BLK_ROWS * PITCH];   // bf16 bits of hi(-2z), [row=hw][d]
    __shared__ short  zl[BLK_ROWS * PITCH];
    __shared__ float2 red[8][BLK_ROWS];       // per-wave (best, best2) per row
    __shared__ int    kidx[BLK_ROWS];
    __shared__ float  wsum[8];

    const int t   = threadIdx.x;              // 0..511
    const int n0  = blockIdx.x * BLK_ROWS;
    const int b   = n0 >> 12;
    const int hw0 = n0 & 4095;

    const int lane = t & 63;
    const int wave = t >> 6;                  // 0..7
    const int l15  = lane & 15;
    const int quad = lane >> 4;

    // ---- stage: thread loads 4 float4 (4 d x 4 rows), converts, writes LDS ----
    {
        const int hwl   = (t & 31) * 4;       // 4 consecutive rows
        const int dbase = (t >> 5) * 4;       // 4 consecutive d
        float4 v[4];
        #pragma unroll
        for (int p = 0; p < 4; ++p)
            v[p] = *(const float4*)(z + (size_t)b * DHW + (size_t)(dbase + p) * HW + hw0 + hwl);
        #pragma unroll
        for (int c = 0; c < 4; ++c) {
            short4 hi, lo;
            short* hp = (short*)&hi; short* lp = (short*)&lo;
            #pragma unroll
            for (int p = 0; p < 4; ++p) {
                const float* vp = (const float*)&v[p];
                float f = -2.0f * vp[c];
                unsigned short hh = f32_to_bf16_rne(f);
                unsigned short ll = f32_to_bf16_rne(f - bf16_to_f32(hh));
                hp[p] = (short)hh; lp[p] = (short)ll;
            }
            *(short4*)&zh[(hwl + c) * PITCH + dbase] = hi;
            *(short4*)&zl[(hwl + c) * PITCH + dbase] = lo;
        }
    }

    // ---- B-fragments: wave's 128 codes, held in registers for entire kernel ----
    short8 Bh[8][2], Bl[8][2];
    float  NR[8];
    {
        const int codebase = wave * 128 + l15;
        #pragma unroll
        for (int ct = 0; ct < 8; ++ct) {
            const short* p = ehg + (codebase + ct * 16) * DIM + quad * 8;
            const short* q = elg + (codebase + ct * 16) * DIM + quad * 8;
            Bh[ct][0] = *(const short8*)(p);
            Bh[ct][1] = *(const short8*)(p + 32);
            Bl[ct][0] = *(const short8*)(q);
            Bl[ct][1] = *(const short8*)(q + 32);
            NR[ct]    = norms[codebase + ct * 16];
        }
    }
    __syncthreads();

    // ---- scan: 8 row-tiles x (8 code-tiles in registers), A prefetch depth-1 ----
    short8 a_h[2][2], a_l[2][2];
    {
        const int idx = l15 * PITCH + quad * 8;
        a_h[0][0] = *(const short8*)&zh[idx];
        a_h[0][1] = *(const short8*)&zh[idx + 32];
        a_l[0][0] = *(const short8*)&zl[idx];
        a_l[0][1] = *(const short8*)&zl[idx + 32];
    }

    #pragma unroll
    for (int rt = 0; rt < 8; ++rt) {
        const int cur = rt & 1, nxt = cur ^ 1;
        if (rt < 7) {
            const int idx = ((rt + 1) * 16 + l15) * PITCH + quad * 8;
            a_h[nxt][0] = *(const short8*)&zh[idx];
            a_h[nxt][1] = *(const short8*)&zh[idx + 32];
            a_l[nxt][0] = *(const short8*)&zl[idx];
            a_l[nxt][1] = *(const short8*)&zl[idx + 32];
        }

        float best[4], best2[4];
        #pragma unroll
        for (int r = 0; r < 4; ++r) { best[r] = 3.0e38f; best2[r] = 3.0e38f; }

        #pragma unroll
        for (int ct = 0; ct < 8; ++ct) {
            f32x4 acc = { NR[ct], NR[ct], NR[ct], NR[ct] };
            acc = __builtin_amdgcn_mfma_f32_16x16x32_bf16(a_h[cur][0], Bh[ct][0], acc, 0, 0, 0);
            acc = __builtin_amdgcn_mfma_f32_16x16x32_bf16(a_h[cur][1], Bh[ct][1], acc, 0, 0, 0);
            acc = __builtin_amdgcn_mfma_f32_16x16x32_bf16(a_h[cur][0], Bl[ct][0], acc, 0, 0, 0);
            acc = __builtin_amdgcn_mfma_f32_16x16x32_bf16(a_h[cur][1], Bl[ct][1], acc, 0, 0, 0);
            acc = __builtin_amdgcn_mfma_f32_16x16x32_bf16(a_l[cur][0], Bh[ct][0], acc, 0, 0, 0);
            acc = __builtin_amdgcn_mfma_f32_16x16x32_bf16(a_l[cur][1], Bh[ct][1], acc, 0, 0, 0);
            const unsigned colbits = (unsigned)(wave * 128 + ct * 16 + l15);
            #pragma unroll
            for (int r = 0; r < 4; ++r) {
                float p = __uint_as_float((__float_as_uint(acc[r]) & 0xFFFFFC00u) | colbits);
                best2[r] = fminf(best2[r], fmaxf(best[r], p));
                best[r]  = fminf(best[r], p);
            }
        }

        // merge across the 16 code-lanes
        #pragma unroll
        for (int r = 0; r < 4; ++r) {
            float bb = best[r], b2 = best2[r];
            #pragma unroll
            for (int m = 1; m <= 8; m <<= 1) {
                float ob  = __shfl_xor(bb, m, 64);
                float ob2 = __shfl_xor(b2, m, 64);
                b2 = fminf(fminf(b2, ob2), fmaxf(bb, ob));
                bb = fminf(bb, ob);
            }
            if (l15 == 0) red[wave][rt * 16 + quad * 4 + r] = make_float2(bb, b2);
        }
    }
    __syncthreads();

    // ---- final cross-wave top-2 merge + flag + worklist (t < 128: one row each) ----
    if (t < BLK_ROWS) {
        float bb = 3.0e38f, b2 = 3.0e38f;
        #pragma unroll
        for (int w = 0; w < 8; ++w) {
            float2 e = red[w][t];
            b2 = fminf(fminf(b2, e.y), fmaxf(bb, e.x));
            bb = fminf(bb, e.x);
        }
        unsigned ub = __float_as_uint(bb);
        int k = (int)(ub & 1023u);
        float sb  = __uint_as_float(ub & 0xFFFFFC00u);
        float sb2 = __uint_as_float(__float_as_uint(b2) & 0xFFFFFC00u);
        int flag = 0;
        if (sb2 - sb < EPS) {
            int slot = atomicAdd(counter, 1);
            if (slot < cap) { worklist[slot] = n0 + t; flag = 1; }
        }
        kidx[t] = k | (flag << 15);
    }
    __syncthreads();

    // ---- epilogue: row = t&127, dgrp = t>>7 covers 16 d; coalesced stores ----
    float lsum = 0.f;
    {
        const int row  = t & 127;
        const int dgrp = t >> 7;              // 0..3
        const int d0   = dgrp * 16;
        const int ki   = kidx[row];
        const int k    = ki & 1023;
        const int flag = (ki >> 15) & 1;
        if (!flag) {
            const float4* cbr = (const float4*)(cb + k * DIM + d0);
            const short8* zhr = (const short8*)&zh[row * PITCH + d0];
            const short8* zlr = (const short8*)&zl[row * PITCH + d0];
            float* op = out + (size_t)b * DHW + (size_t)d0 * HW + hw0 + row;
            #pragma unroll
            for (int g = 0; g < 2; ++g) {
                short8 hh = zhr[g];
                short8 ll = zlr[g];
                float4 e0 = cbr[2 * g];
                float4 e1 = cbr[2 * g + 1];
                const float ev[8] = { e0.x, e0.y, e0.z, e0.w, e1.x, e1.y, e1.z, e1.w };
                #pragma unroll
                for (int j = 0; j < 8; ++j) {
                    float zv = -0.5f * (bf16_to_f32((unsigned short)hh[j]) +
                                        bf16_to_f32((unsigned short)ll[j]));
                    op[(size_t)(g * 8 + j) * HW] = ev[j];
                    float df = ev[j] - zv;
                    lsum = fmaf(df, df, lsum);
                }
            }
        }
    }
    #pragma unroll
    for (int off = 32; off > 0; off >>= 1) lsum += __shfl_down(lsum, off, 64);
    if (lane == 0) wsum[wave] = lsum;
    __syncthreads();
    if (t == 0) {
        float s = 0.f;
        #pragma unroll
        for (int w = 0; w < 8; ++w) s += wsum[w];
        atomicAdd(loss_acc, (double)s);
    }
}

// One wave per flagged vector (4/block); codebook LDS-staged with odd pitch
// (conflict-free); exact f64 distances; last block finalizes the loss.
__global__ __launch_bounds__(256, 2) void vq_rescue(
    const float* __restrict__ z, const float* __restrict__ cb,
    float* __restrict__ out, double* __restrict__ loss_acc,
    const int* __restrict__ counter, const int* __restrict__ worklist, int cap,
    int* __restrict__ done, float* __restrict__ loss_out)
{
    __shared__ float cbs[CHUNK_ROWS * CPITCH];   // 65 KiB
    __shared__ float zsh[4][DIM];

    int count = *counter; if (count > cap) count = cap;
    const int t    = threadIdx.x;
    const int wave = t >> 6;
    const int lane = t & 63;

    for (int base = blockIdx.x * 4; base < count; base += gridDim.x * 4) {
        const int  i      = base + wave;
        const bool active = (i < count);          // wave-uniform
        int n = 0;
        if (active) {
            n = worklist[i];
            const int bb = n >> 12, hw = n & 4095;
            zsh[wave][lane] = z[(size_t)bb * DHW + (size_t)lane * HW + hw];
        }

        double bestd = 1e300; int bestk = 0;
        for (int chunk = 0; chunk < 4; ++chunk) {
            __syncthreads();   // cbs reusable + zsh visible (uniform trip counts)
            const float4* src = (const float4*)(cb + (size_t)chunk * CHUNK_ROWS * DIM);
            #pragma unroll
            for (int ii = 0; ii < 16; ++ii) {
                const int f   = t + ii * 256;     // float4 index in chunk
                float4 v = src[f];
                float* dst = &cbs[(f >> 4) * CPITCH + (f & 15) * 4];
                dst[0] = v.x; dst[1] = v.y; dst[2] = v.z; dst[3] = v.w;
            }
            __syncthreads();
            if (active) {
                const float* zr = zsh[wave];      // broadcast reads (free)
                #pragma unroll
                for (int j = 0; j < 4; ++j) {
                    const int row = j * 64 + lane;
                    const float* cr = &cbs[row * CPITCH];
                    double s0 = 0, s1 = 0, s2 = 0, s3 = 0;
                    #pragma unroll
                    for (int d = 0; d < DIM; d += 4) {
                        double d0 = (double)zr[d + 0] - (double)cr[d + 0];
                        double d1 = (double)zr[d + 1] - (double)cr[d + 1];
                        double d2 = (double)zr[d + 2] - (double)cr[d + 2];
                        double d3 = (double)zr[d + 3] - (double)cr[d + 3];
                        s0 = fma(d0, d0, s0); s1 = fma(d1, d1, s1);
                        s2 = fma(d2, d2, s2); s3 = fma(d3, d3, s3);
                    }
                    double s = (s0 + s1) + (s2 + s3);
                    const int gk = chunk * CHUNK_ROWS + row;
                    if (s < bestd) { bestd = s; bestk = gk; }
                }
            }
        }

        // wave-level (val, idx) min with first-occurrence tiebreak
        #pragma unroll
        for (int m = 1; m <= 32; m <<= 1) {
            double ov = __shfl_xor(bestd, m, 64);
            int    oi = __shfl_xor(bestk, m, 64);
            if (ov < bestd || (ov == bestd && oi < bestk)) { bestd = ov; bestk = oi; }
        }
        if (active) {
            const int bb = n >> 12, hw = n & 4095;
            out[(size_t)bb * DHW + (size_t)lane * HW + hw] = cb[bestk * DIM + lane];
            if (lane == 0) atomicAdd(loss_acc, bestd);
        }
    }

    __threadfence();
    __shared__ int ticket_s;
    if (t == 0) ticket_s = atomicAdd(done, 1);
    __syncthreads();
    if (t == 0 && ticket_s == (int)gridDim.x - 1) {
        double total = atomicAdd(loss_acc, 0.0);   // device-coherent read
        *loss_out = (float)(1.25 * total * (1.0 / (double)((long)N_VEC * DIM)));
    }
}

extern "C" void kernel_launch(void* const* d_in, const int* in_sizes, int n_in,
                              void* d_out, int out_size, void* d_ws, size_t ws_size,
                              hipStream_t stream) {
    const float* z  = (const float*)d_in[0];
    const float* cb = (const float*)d_in[1];
    float* out      = (float*)d_out;
    char*  ws       = (char*)d_ws;

    double* loss_acc = (double*)ws;
    int*    counter  = (int*)(ws + 8);
    int*    done     = (int*)(ws + 12);
    float*  norms    = (float*)(ws + 64);
    short*  ehg      = (short*)(ws + 8192);
    short*  elg      = (short*)(ws + 139264);
    int*    worklist = (int*)(ws + 270336);

    int cap = WLCAP;
    long avail = ((long)ws_size - 270336) / 4;
    if (avail < cap) cap = (avail > 0) ? (int)avail : 0;

    vq_prep<<<dim3(KCODE / 16), dim3(256), 0, stream>>>(
        cb, norms, ehg, elg, loss_acc, counter, done);
    vq_main<<<dim3(N_VEC / BLK_ROWS), dim3(512), 0, stream>>>(
        z, cb, norms, ehg, elg, out, loss_acc, counter, worklist, cap);
    vq_rescue<<<dim3(512), dim3(256), 0, stream>>>(
        z, cb, out, loss_acc, counter, worklist, cap, done, out + (out_size - 1));
}

// Round 10
// 283.981 us; speedup vs baseline: 1.0577x; 1.0577x over previous
//
#include <hip/hip_runtime.h>

#define N_VEC 131072   // B*H*W
#define DIM   64
#define KCODE 1024
#define HW    4096
#define DHW   262144
#define EPS   0.125f   // near-tie margin (validated r4-r8)
#define WLCAP 32768
#define BLK_ROWS 128   // rows per block; 4 waves x 32 rows
#define PITCH 72       // shorts per LDS row (144 B)
#define CHUNK 128      // codes per LDS-staged codebook chunk
#define NCHUNK 8
#define CPITCH 65      // rescue LDS pitch (odd -> conflict-free)
#define CHUNK_ROWS 256

typedef short short8 __attribute__((ext_vector_type(8)));
typedef float f32x4  __attribute__((ext_vector_type(4)));

// ws layout (bytes):
//   0      : double loss accumulator
//   8      : int flagged counter
//   12     : int done-ticket counter
//   64     : norms f32[1024]
//   8192   : eh  bf16-bits short[65536]
//   139264 : el  bf16-bits short[65536]
//   270336 : worklist int[WLCAP]

__device__ __forceinline__ unsigned short f32_to_bf16_rne(float x) {
    unsigned u = __float_as_uint(x);
    u += 0x7FFFu + ((u >> 16) & 1u);
    return (unsigned short)(u >> 16);
}
__device__ __forceinline__ float bf16_to_f32(unsigned short h) {
    return __uint_as_float((unsigned)h << 16);
}

__global__ __launch_bounds__(256) void vq_prep(
    const float* __restrict__ cb, float* __restrict__ norms,
    short* __restrict__ ehg, short* __restrict__ elg,
    double* __restrict__ loss_acc, int* __restrict__ counter,
    int* __restrict__ done)
{
    const int t = threadIdx.x;
    if (blockIdx.x == 0 && t == 0) { *loss_acc = 0.0; *counter = 0; *done = 0; }

    const int k    = blockIdx.x * 16 + (t >> 4);
    const int part = t & 15;
    const float4 v = *(const float4*)(cb + k * DIM + part * 4);

    float s = 0.f;
    s = fmaf(v.x, v.x, s); s = fmaf(v.y, v.y, s);
    s = fmaf(v.z, v.z, s); s = fmaf(v.w, v.w, s);
    #pragma unroll
    for (int m = 1; m <= 8; m <<= 1) s += __shfl_xor(s, m, 64);
    if (part == 0) norms[k] = s;

    short h[4], l[4];
    const float vv[4] = { v.x, v.y, v.z, v.w };
    #pragma unroll
    for (int j = 0; j < 4; ++j) {
        unsigned short hh = f32_to_bf16_rne(vv[j]);
        unsigned short ll = f32_to_bf16_rne(vv[j] - bf16_to_f32(hh));
        h[j] = (short)hh; l[j] = (short)ll;
    }
    *(short4*)(ehg + k * DIM + part * 4) = make_short4(h[0], h[1], h[2], h[3]);
    *(short4*)(elg + k * DIM + part * 4) = make_short4(l[0], l[1], l[2], l[3]);
}

__global__ __launch_bounds__(256, 2) void vq_main(
    const float* __restrict__ z, const float* __restrict__ cb,
    const float* __restrict__ norms, const short* __restrict__ ehg,
    const short* __restrict__ elg, float* __restrict__ out,
    double* __restrict__ loss_acc, int* __restrict__ counter,
    int* __restrict__ worklist, int cap)
{
    __shared__ short  zh[BLK_ROWS * PITCH];   // hi(-2z) bf16 bits, [row=hw][d]
    __shared__ short  zl[BLK_ROWS * PITCH];
    __shared__ short  ebh[CHUNK * PITCH];     // codebook chunk hi, [code][d]
    __shared__ short  ebl[CHUNK * PITCH];
    __shared__ int    kidx[BLK_ROWS];
    __shared__ float  wsum[4];

    const int t   = threadIdx.x;              // 0..255
    const int n0  = blockIdx.x * BLK_ROWS;
    const int b   = n0 >> 12;
    const int hw0 = n0 & 4095;

    const int lane = t & 63;
    const int wave = t >> 6;                  // 0..3
    const int l15  = lane & 15;
    const int quad = lane >> 4;
    const int rowbase = wave * 32;            // 2 row-tiles per wave

    // ---- stage z -> LDS (8 float4/thread, register transpose, b128 writes) ----
    {
        const int hwl   = (t & 31) * 4;       // 4 consecutive rows
        const int dbase = (t >> 5) * 8;       // 8 consecutive d
        float4 v[8];
        #pragma unroll
        for (int p = 0; p < 8; ++p)
            v[p] = *(const float4*)(z + (size_t)b * DHW + (size_t)(dbase + p) * HW + hw0 + hwl);
        #pragma unroll
        for (int c = 0; c < 4; ++c) {
            short8 hi, lo;
            #pragma unroll
            for (int p = 0; p < 8; ++p) {
                const float* vp = (const float*)&v[p];
                float f = -2.0f * vp[c];
                unsigned short hh = f32_to_bf16_rne(f);
                unsigned short ll = f32_to_bf16_rne(f - bf16_to_f32(hh));
                hi[p] = (short)hh; lo[p] = (short)ll;
            }
            *(short8*)&zh[(hwl + c) * PITCH + dbase] = hi;
            *(short8*)&zl[(hwl + c) * PITCH + dbase] = lo;
        }
    }

    // ---- B-staging register pipeline: thread owns 64 B of hi + 64 B of lo ----
    const int cc = t >> 1;                    // code within chunk
    const int pp = (t & 1) * 32;              // short offset within code row
    short8 pf[2][8];                          // [buf][0..3]=hi, [4..7]=lo
    #pragma unroll
    for (int j = 0; j < 4; ++j) {
        pf[0][j]     = *(const short8*)(ehg + (size_t)cc * DIM + pp + j * 8);
        pf[0][4 + j] = *(const short8*)(elg + (size_t)cc * DIM + pp + j * 8);
    }
    __syncthreads();                          // z-tile ready

    // ---- A-fragments (32 VGPRs, resident) ----
    short8 a_h[2][2], a_l[2][2];
    #pragma unroll
    for (int rt = 0; rt < 2; ++rt)
        #pragma unroll
        for (int kt = 0; kt < 2; ++kt) {
            const int idx = (rowbase + rt * 16 + l15) * PITCH + kt * 32 + quad * 8;
            a_h[rt][kt] = *(const short8*)&zh[idx];
            a_l[rt][kt] = *(const short8*)&zl[idx];
        }

    float best[2][4], best2[2][4];
    #pragma unroll
    for (int rt = 0; rt < 2; ++rt)
        #pragma unroll
        for (int r = 0; r < 4; ++r) { best[rt][r] = 3.0e38f; best2[rt][r] = 3.0e38f; }

    // ---- K-loop over 8 codebook chunks, LDS single-buffer + reg prefetch ----
    #pragma unroll
    for (int ch = 0; ch < NCHUNK; ++ch) {
        const int cur = ch & 1;
        // write prefetched chunk into LDS
        #pragma unroll
        for (int j = 0; j < 4; ++j) {
            *(short8*)&ebh[cc * PITCH + pp + j * 8] = pf[cur][j];
            *(short8*)&ebl[cc * PITCH + pp + j * 8] = pf[cur][4 + j];
        }
        // issue next chunk's global loads (in flight during compute)
        if (ch < NCHUNK - 1) {
            #pragma unroll
            for (int j = 0; j < 4; ++j) {
                pf[cur ^ 1][j]     = *(const short8*)(ehg + (size_t)((ch + 1) * CHUNK + cc) * DIM + pp + j * 8);
                pf[cur ^ 1][4 + j] = *(const short8*)(elg + (size_t)((ch + 1) * CHUNK + cc) * DIM + pp + j * 8);
            }
        }
        __syncthreads();                      // chunk ch visible

        #pragma unroll
        for (int ct = 0; ct < 8; ++ct) {
            const int crow = ct * 16 + l15;
            short8 Bh0 = *(const short8*)&ebh[crow * PITCH + quad * 8];
            short8 Bh1 = *(const short8*)&ebh[crow * PITCH + 32 + quad * 8];
            short8 Bl0 = *(const short8*)&ebl[crow * PITCH + quad * 8];
            short8 Bl1 = *(const short8*)&ebl[crow * PITCH + 32 + quad * 8];
            const float nrm = norms[ch * CHUNK + crow];
            const unsigned colbits = (unsigned)(ch * CHUNK + crow);
            #pragma unroll
            for (int rt = 0; rt < 2; ++rt) {
                f32x4 acc = { nrm, nrm, nrm, nrm };
                acc = __builtin_amdgcn_mfma_f32_16x16x32_bf16(a_h[rt][0], Bh0, acc, 0, 0, 0);
                acc = __builtin_amdgcn_mfma_f32_16x16x32_bf16(a_h[rt][1], Bh1, acc, 0, 0, 0);
                acc = __builtin_amdgcn_mfma_f32_16x16x32_bf16(a_h[rt][0], Bl0, acc, 0, 0, 0);
                acc = __builtin_amdgcn_mfma_f32_16x16x32_bf16(a_h[rt][1], Bl1, acc, 0, 0, 0);
                acc = __builtin_amdgcn_mfma_f32_16x16x32_bf16(a_l[rt][0], Bh0, acc, 0, 0, 0);
                acc = __builtin_amdgcn_mfma_f32_16x16x32_bf16(a_l[rt][1], Bh1, acc, 0, 0, 0);
                #pragma unroll
                for (int r = 0; r < 4; ++r) {
                    float p = __uint_as_float((__float_as_uint(acc[r]) & 0xFFFFFC00u) | colbits);
                    best2[rt][r] = fminf(best2[rt][r], fmaxf(best[rt][r], p));
                    best[rt][r]  = fminf(best[rt][r], p);
                }
            }
        }
        __syncthreads();                      // compute done before next overwrite
    }

    // ---- merge across 16 code-lanes; each wave has complete top-2 for its rows ----
    #pragma unroll
    for (int rt = 0; rt < 2; ++rt)
        #pragma unroll
        for (int r = 0; r < 4; ++r) {
            float bb = best[rt][r], b2 = best2[rt][r];
            #pragma unroll
            for (int m = 1; m <= 8; m <<= 1) {
                float ob  = __shfl_xor(bb, m, 64);
                float ob2 = __shfl_xor(b2, m, 64);
                b2 = fminf(fminf(b2, ob2), fmaxf(bb, ob));
                bb = fminf(bb, ob);
            }
            best[rt][r] = bb; best2[rt][r] = b2;
        }

    // ---- per-row result: index, flag, worklist (l15==0 lanes own one row each) ----
    if (l15 == 0) {
        #pragma unroll
        for (int rt = 0; rt < 2; ++rt)
            #pragma unroll
            for (int r = 0; r < 4; ++r) {
                unsigned ub = __float_as_uint(best[rt][r]);
                int k = (int)(ub & 1023u);
                float sb  = __uint_as_float(ub & 0xFFFFFC00u);
                float sb2 = __uint_as_float(__float_as_uint(best2[rt][r]) & 0xFFFFFC00u);
                int rowl = rt * 16 + quad * 4 + r;
                int flag = 0;
                if (sb2 - sb < EPS) {
                    int slot = atomicAdd(counter, 1);
                    if (slot < cap) { worklist[slot] = n0 + rowbase + rowl; flag = 1; }
                }
                kidx[rowbase + rowl] = k | (flag << 15);
            }
    }
    __syncthreads();

    // ---- epilogue: row = t&127, dgrp = t>>7 covers 32 d; coalesced stores ----
    float lsum = 0.f;
    {
        const int row  = t & 127;
        const int d0   = (t >> 7) * 32;
        const int ki   = kidx[row];
        const int k    = ki & 1023;
        const int flag = (ki >> 15) & 1;
        if (!flag) {
            const float4* cbr = (const float4*)(cb + k * DIM + d0);
            const short8* zhr = (const short8*)&zh[row * PITCH + d0];
            const short8* zlr = (const short8*)&zl[row * PITCH + d0];
            float* op = out + (size_t)b * DHW + (size_t)d0 * HW + hw0 + row;
            #pragma unroll
            for (int g = 0; g < 4; ++g) {
                short8 hh = zhr[g];
                short8 ll = zlr[g];
                float4 e0 = cbr[2 * g];
                float4 e1 = cbr[2 * g + 1];
                const float ev[8] = { e0.x, e0.y, e0.z, e0.w, e1.x, e1.y, e1.z, e1.w };
                #pragma unroll
                for (int j = 0; j < 8; ++j) {
                    float zv = -0.5f * (bf16_to_f32((unsigned short)hh[j]) +
                                        bf16_to_f32((unsigned short)ll[j]));
                    op[(size_t)(g * 8 + j) * HW] = ev[j];
                    float df = ev[j] - zv;
                    lsum = fmaf(df, df, lsum);
                }
            }
        }
    }
    #pragma unroll
    for (int off = 32; off > 0; off >>= 1) lsum += __shfl_down(lsum, off, 64);
    if (lane == 0) wsum[wave] = lsum;
    __syncthreads();
    if (t == 0)
        atomicAdd(loss_acc, (double)((wsum[0] + wsum[1]) + (wsum[2] + wsum[3])));
}

// One wave per flagged vector (4/block); codebook LDS-staged with odd pitch
// (conflict-free); exact f64 distances; last block finalizes the loss.
__global__ __launch_bounds__(256, 2) void vq_rescue(
    const float* __restrict__ z, const float* __restrict__ cb,
    float* __restrict__ out, double* __restrict__ loss_acc,
    const int* __restrict__ counter, const int* __restrict__ worklist, int cap,
    int* __restrict__ done, float* __restrict__ loss_out)
{
    __shared__ float cbs[CHUNK_ROWS * CPITCH];   // 65 KiB
    __shared__ float zsh[4][DIM];

    int count = *counter; if (count > cap) count = cap;
    const int t    = threadIdx.x;
    const int wave = t >> 6;
    const int lane = t & 63;

    for (int base = blockIdx.x * 4; base < count; base += gridDim.x * 4) {
        const int  i      = base + wave;
        const bool active = (i < count);          // wave-uniform
        int n = 0;
        if (active) {
            n = worklist[i];
            const int bb = n >> 12, hw = n & 4095;
            zsh[wave][lane] = z[(size_t)bb * DHW + (size_t)lane * HW + hw];
        }

        double bestd = 1e300; int bestk = 0;
        for (int chunk = 0; chunk < 4; ++chunk) {
            __syncthreads();
            const float4* src = (const float4*)(cb + (size_t)chunk * CHUNK_ROWS * DIM);
            #pragma unroll
            for (int ii = 0; ii < 16; ++ii) {
                const int f = t + ii * 256;
                float4 v = src[f];
                float* dst = &cbs[(f >> 4) * CPITCH + (f & 15) * 4];
                dst[0] = v.x; dst[1] = v.y; dst[2] = v.z; dst[3] = v.w;
            }
            __syncthreads();
            if (active) {
                const float* zr = zsh[wave];
                #pragma unroll
                for (int j = 0; j < 4; ++j) {
                    const int row = j * 64 + lane;
                    const float* cr = &cbs[row * CPITCH];
                    double s0 = 0, s1 = 0, s2 = 0, s3 = 0;
                    #pragma unroll
                    for (int d = 0; d < DIM; d += 4) {
                        double d0 = (double)zr[d + 0] - (double)cr[d + 0];
                        double d1 = (double)zr[d + 1] - (double)cr[d + 1];
                        double d2 = (double)zr[d + 2] - (double)cr[d + 2];
                        double d3 = (double)zr[d + 3] - (double)cr[d + 3];
                        s0 = fma(d0, d0, s0); s1 = fma(d1, d1, s1);
                        s2 = fma(d2, d2, s2); s3 = fma(d3, d3, s3);
                    }
                    double s = (s0 + s1) + (s2 + s3);
                    const int gk = chunk * CHUNK_ROWS + row;
                    if (s < bestd) { bestd = s; bestk = gk; }
                }
            }
        }

        #pragma unroll
        for (int m = 1; m <= 32; m <<= 1) {
            double ov = __shfl_xor(bestd, m, 64);
            int    oi = __shfl_xor(bestk, m, 64);
            if (ov < bestd || (ov == bestd && oi < bestk)) { bestd = ov; bestk = oi; }
        }
        if (active) {
            const int bb = n >> 12, hw = n & 4095;
            out[(size_t)bb * DHW + (size_t)lane * HW + hw] = cb[bestk * DIM + lane];
            if (lane == 0) atomicAdd(loss_acc, bestd);
        }
    }

    __threadfence();
    __shared__ int ticket_s;
    if (t == 0) ticket_s = atomicAdd(done, 1);
    __syncthreads();
    if (t == 0 && ticket_s == (int)gridDim.x - 1) {
        double total = atomicAdd(loss_acc, 0.0);
        *loss_out = (float)(1.25 * total * (1.0 / (double)((long)N_VEC * DIM)));
    }
}

extern "C" void kernel_launch(void* const* d_in, const int* in_sizes, int n_in,
                              void* d_out, int out_size, void* d_ws, size_t ws_size,
                              hipStream_t stream) {
    const float* z  = (const float*)d_in[0];
    const float* cb = (const float*)d_in[1];
    float* out      = (float*)d_out;
    char*  ws       = (char*)d_ws;

    double* loss_acc = (double*)ws;
    int*    counter  = (int*)(ws + 8);
    int*    done     = (int*)(ws + 12);
    float*  norms    = (float*)(ws + 64);
    short*  ehg      = (short*)(ws + 8192);
    short*  elg      = (short*)(ws + 139264);
    int*    worklist = (int*)(ws + 270336);

    int cap = WLCAP;
    long avail = ((long)ws_size - 270336) / 4;
    if (avail < cap) cap = (avail > 0) ? (int)avail : 0;

    vq_prep<<<dim3(KCODE / 16), dim3(256), 0, stream>>>(
        cb, norms, ehg, elg, loss_acc, counter, done);
    vq_main<<<dim3(N_VEC / BLK_ROWS), dim3(256), 0, stream>>>(
        z, cb, norms, ehg, elg, out, loss_acc, counter, worklist, cap);
    vq_rescue<<<dim3(512), dim3(256), 0, stream>>>(
        z, cb, out, loss_acc, counter, worklist, cap, done, out + (out_size - 1));
}